// Round 2
// baseline (244.454 us; speedup 1.0000x reference)
//
#include <hip/hip_runtime.h>

// NarrativeClassificationLoss — v6: wide column-slice decomposition.
// R5 post-mortem of v5 (120us main, 1.2TB/s): 32-col slices gave only
// 128B contiguity per row (4KB stride scatter) and fn/fs/hier were 2048
// serialized same-address atomics. v6: 8 slices x 128 sub cols -> 512B
// contiguous per row per wave, 64-row chunks walked sequentially; grid
// 2048 (8 blocks/CU), unroll 4 (128B in flight/thread); scalars go to a
// 64-slot array; column atomics are 15 coalesced wave-atomics per block.
// Single 14.6KB table, no reduce kernels (v5's structural win, kept).
//
// B=16384, N_NARR=128, N_SUB=1024, K=8, GAMMA=2, weights (1,1,0.5).

#define BDIM 256
#define NROWS 16384
#define NNARR 128
#define NSUB 1024

#define NSLICES 8
#define SUBC 128                           // sub cols per slice
#define NARRC 16                           // narr cols per slice
#define ROWS_PER_CHUNK 64
#define NCHUNKS (NROWS / ROWS_PER_CHUNK)   // 256
#define NBLOCKS (NCHUNKS * NSLICES)        // 2048
#define ROWS_PER_PASS 8                    // 256 thr / 32 col-quads
#define ITERS (ROWS_PER_CHUNK / ROWS_PER_PASS)  // 8

// single global table layout (floats)
#define WS_AN    0      // [128]  sum_b y*sp(-x)          (narrative)
#define WS_CN    128    // [128]  sum_b (1-y)*sp(x)
#define WS_NSUM  256    // [128]  col sums of narrative labels
#define WS_AS    384    // [1024] sum_b pos*y*sp(-x)      (subnarrative)
#define WS_CS    1408   // [1024] sum_b pos*(1-y)*sp(x)
#define WS_SSUM  2432   // [1024] col sums of sub labels
#define WS_SC    3456   // [64][3] {fn,fs,hier} slots (kills hot-address atomics)
#define NSLOTS   64
#define WS_FLOATS (WS_SC + NSLOTS * 3)     // 3648

__device__ __forceinline__ void bce_pieces(float x, float& sp_p, float& sp_m, float& sig) {
    float a = fabsf(x);
    float e = __expf(-a);              // exp(-|x|) in (0,1]
    float l = __logf(1.0f + e);        // ~log1p(e); err ~1e-7, fine after /2M
    sp_p = fmaxf(x, 0.0f) + l;
    sp_m = sp_p - x;
    float inv = __builtin_amdgcn_rcpf(1.0f + e);
    sig = (x >= 0.0f) ? inv : e * inv;
}

__global__ __launch_bounds__(BDIM, 6) void ncl_main(
    const float* __restrict__ nlog, const float* __restrict__ slog,
    const int*   __restrict__ nlab, const int*   __restrict__ slab,
    float* __restrict__ ws)
{
    __shared__ float lsub[4][32][12];  // per-wave per-col-quad {As,Cs,ss}  6KB
    __shared__ float lnar[4][16][3];   // per-wave per-narrcol {An,Cn,ns}
    __shared__ float lsc[4][3];        // per-wave {fn,fs,hier}

    const int t     = threadIdx.x;
    const int j     = blockIdx.x & (NSLICES - 1);   // col slice
    const int chunk = blockIdx.x >> 3;              // row chunk
    const int q  = t & 31;       // sub col-quad within slice (4 cols)
    const int ro = t >> 5;       // row offset 0..7 within a pass
    const int cl = q >> 1;       // local narr col 0..15 (quad pair = 1 group)
    const bool evenq = (q & 1) == 0;

    const int r0 = chunk * ROWS_PER_CHUNK + ro;
    const float* sp = slog + (size_t)r0 * NSUB  + j * SUBC  + 4 * q;
    const int*   yp = slab + (size_t)r0 * NSUB  + j * SUBC  + 4 * q;
    const float* np = nlog + (size_t)r0 * NNARR + j * NARRC + cl;
    const int*   mp = nlab + (size_t)r0 * NNARR + j * NARRC + cl;

    float As[4] = {0,0,0,0}, Cs[4] = {0,0,0,0}, ssum[4] = {0,0,0,0};
    float An = 0.f, Cn = 0.f, ns = 0.f, fn = 0.f, fs = 0.f, hier = 0.f;

    #pragma unroll 4
    for (int it = 0; it < ITERS; ++it) {
        const size_t so = (size_t)it * ROWS_PER_PASS * NSUB;
        const size_t no = (size_t)it * ROWS_PER_PASS * NNARR;
        const float4 xs = *(const float4*)(sp + so);
        const int4   ys = *(const int4*)  (yp + so);
        const float  nx   = np[no];
        const float  posv = (float)mp[no];   // narr label == pos mask

        float nsp_p, nsp_m, nsig;
        bce_pieces(nx, nsp_p, nsp_m, nsig);

        const float xv[4] = {xs.x, xs.y, xs.z, xs.w};
        const float yv[4] = {(float)ys.x, (float)ys.y, (float)ys.z, (float)ys.w};
        float mymax = 0.0f;
        #pragma unroll
        for (int k = 0; k < 4; ++k) {
            float sp_p, sp_m, sig;
            bce_pieces(xv[k], sp_p, sp_m, sig);
            float y = yv[k];
            As[k]   += posv * y * sp_m;
            Cs[k]   += posv * (1.0f - y) * sp_p;
            ssum[k] += y;
            float om = 1.0f - sig;
            fs += om * om * y * (-sp_m);     // log_sigmoid(x) = -softplus(-x)
            mymax = fmaxf(mymax, sig);
        }
        // group of 8 sub cols = adjacent quad pair (t, t^1): same row, same cl
        float gmax = fmaxf(mymax, __shfl_xor(mymax, 1, 64));
        if (evenq) {
            hier += fmaxf(gmax - nsig, 0.0f) * posv;
            An += posv * nsp_m;
            Cn += (1.0f - posv) * nsp_p;
            ns += posv;
            float om = 1.0f - nsig;
            fn += om * om * posv * (-nsp_m);
        }
    }

    // lanes l and l+32 share q (differ in ro): one stride-32 butterfly folds
    // the wave's two row-sets. Narr values live only on even-q lanes.
    #pragma unroll
    for (int k = 0; k < 4; ++k) {
        As[k]   += __shfl_xor(As[k],   32, 64);
        Cs[k]   += __shfl_xor(Cs[k],   32, 64);
        ssum[k] += __shfl_xor(ssum[k], 32, 64);
    }
    An += __shfl_xor(An, 32, 64);
    Cn += __shfl_xor(Cn, 32, 64);
    ns += __shfl_xor(ns, 32, 64);
    // full-wave butterfly for the scalar partials
    #pragma unroll
    for (int m = 1; m <= 32; m <<= 1) {
        fn   += __shfl_xor(fn,   m, 64);
        fs   += __shfl_xor(fs,   m, 64);
        hier += __shfl_xor(hier, m, 64);
    }

    const int w = t >> 6, lane = t & 63;
    if (lane < 32) {
        #pragma unroll
        for (int k = 0; k < 4; ++k) {
            lsub[w][lane][k]     = As[k];
            lsub[w][lane][4 + k] = Cs[k];
            lsub[w][lane][8 + k] = ssum[k];
        }
        if ((lane & 1) == 0) {
            lnar[w][lane >> 1][0] = An;
            lnar[w][lane >> 1][1] = Cn;
            lnar[w][lane >> 1][2] = ns;
        }
    }
    if (lane == 0) { lsc[w][0] = fn; lsc[w][1] = fs; lsc[w][2] = hier; }
    __syncthreads();

    if (t < 32) {
        float a[12];
        #pragma unroll
        for (int k = 0; k < 12; ++k)
            a[k] = lsub[0][t][k] + lsub[1][t][k] + lsub[2][t][k] + lsub[3][t][k];
        const int col = j * SUBC + 4 * t;
        #pragma unroll
        for (int k = 0; k < 4; ++k) {
            atomicAdd(ws + WS_AS   + col + k, a[k]);
            atomicAdd(ws + WS_CS   + col + k, a[4 + k]);
            atomicAdd(ws + WS_SSUM + col + k, a[8 + k]);
        }
    } else if (t < 48) {
        const int c = t - 32;
        float a0 = lnar[0][c][0] + lnar[1][c][0] + lnar[2][c][0] + lnar[3][c][0];
        float a1 = lnar[0][c][1] + lnar[1][c][1] + lnar[2][c][1] + lnar[3][c][1];
        float a2 = lnar[0][c][2] + lnar[1][c][2] + lnar[2][c][2] + lnar[3][c][2];
        atomicAdd(ws + WS_AN   + j * NARRC + c, a0);
        atomicAdd(ws + WS_CN   + j * NARRC + c, a1);
        atomicAdd(ws + WS_NSUM + j * NARRC + c, a2);
    } else if (t == 48) {
        float a = lsc[0][0] + lsc[1][0] + lsc[2][0] + lsc[3][0];
        float b = lsc[0][1] + lsc[1][1] + lsc[2][1] + lsc[3][1];
        float c = lsc[0][2] + lsc[1][2] + lsc[2][2] + lsc[3][2];
        const int slot = blockIdx.x & (NSLOTS - 1);   // 32 writers/slot
        atomicAdd(ws + WS_SC + 3 * slot + 0, a);
        atomicAdd(ws + WS_SC + 3 * slot + 1, b);
        atomicAdd(ws + WS_SC + 3 * slot + 2, c);
    }
}

__global__ __launch_bounds__(1024) void ncl_finalize(const float* __restrict__ ws,
                                                     float* __restrict__ out)
{
    __shared__ float sr[6][16];
    const int t = threadIdx.x;
    const float Bf = (float)NROWS;

    float s_sub = ws[WS_SSUM + t];
    float spw   = fminf(fmaxf((Bf - s_sub) / (s_sub + 1e-6f), 1.0f), 50.0f);
    float sub_part = spw * ws[WS_AS + t] + ws[WS_CS + t];

    float narr_part = 0.f, valid_part = 0.f;
    if (t < NNARR) {
        float s = ws[WS_NSUM + t];
        float npw = fminf(fmaxf((Bf - s) / (s + 1e-6f), 1.0f), 50.0f);
        narr_part  = npw * ws[WS_AN + t] + ws[WS_CN + t];
        valid_part = s;
    }

    float fn_p = 0.f, fs_p = 0.f, hier_p = 0.f;
    if (t < NSLOTS) {
        fn_p   = ws[WS_SC + 3 * t + 0];
        fs_p   = ws[WS_SC + 3 * t + 1];
        hier_p = ws[WS_SC + 3 * t + 2];
    }

    #pragma unroll
    for (int off = 32; off; off >>= 1) {
        sub_part   += __shfl_down(sub_part,   off, 64);
        narr_part  += __shfl_down(narr_part,  off, 64);
        valid_part += __shfl_down(valid_part, off, 64);
        fn_p       += __shfl_down(fn_p,       off, 64);
        fs_p       += __shfl_down(fs_p,       off, 64);
        hier_p     += __shfl_down(hier_p,     off, 64);
    }
    if ((t & 63) == 0) {
        int w = t >> 6;
        sr[0][w] = sub_part; sr[1][w] = narr_part; sr[2][w] = valid_part;
        sr[3][w] = fn_p;     sr[4][w] = fs_p;      sr[5][w] = hier_p;
    }
    __syncthreads();
    if (t == 0) {
        float sub_tot = 0.f, narr_tot = 0.f, valid = 0.f;
        float fn = 0.f, fs = 0.f, hier = 0.f;
        #pragma unroll
        for (int i = 0; i < 16; ++i) {
            sub_tot += sr[0][i]; narr_tot += sr[1][i]; valid += sr[2][i];
            fn += sr[3][i]; fs += sr[4][i]; hier += sr[5][i];
        }

        float narrative_loss = narr_tot / (Bf * (float)NNARR);
        float sub_loss = (valid > 0.0f) ? (sub_tot * (1.0f / 8.0f)) / fmaxf(valid, 1.0f) : 0.0f;
        float nf = fn / (Bf * (float)NNARR);
        float sf = fs / (Bf * (float)NSUB);
        float hier_loss = hier / Bf;

        out[0] = (narrative_loss - 0.1f * nf)
               + (sub_loss       - 0.1f * sf)
               + 0.5f * hier_loss;
    }
}

extern "C" void kernel_launch(void* const* d_in, const int* in_sizes, int n_in,
                              void* d_out, int out_size, void* d_ws, size_t ws_size,
                              hipStream_t stream) {
    const float* nlog = (const float*)d_in[0];
    const float* slog = (const float*)d_in[1];
    const int*   nlab = (const int*)d_in[2];
    const int*   slab = (const int*)d_in[3];
    float* ws  = (float*)d_ws;
    float* out = (float*)d_out;

    hipMemsetAsync(ws, 0, WS_FLOATS * sizeof(float), stream);
    ncl_main<<<NBLOCKS, BDIM, 0, stream>>>(nlog, slog, nlab, slab, ws);
    ncl_finalize<<<1, 1024, 0, stream>>>(ws, out);
}

// Round 3
// 206.599 us; speedup vs baseline: 1.1832x; 1.1832x over previous
//
#include <hip/hip_runtime.h>

// NarrativeClassificationLoss — v7: column slices + exclusive partials.
// R6 post-mortem of v6 (135us main): 890K device-scope lane-atomics ->
// memory-side RMW at the coherent point (per-XCD L2 non-coherent).
// WRITE_SIZE 167MB (~input-sized L3 churn), inputs evicted from L3,
// serialized RMW drain. v4 (zero atomics) had the fastest main: so v7
// emits EXCLUSIVE per-block 448-float partials with plain float4 stores
// (3.7MB total), then a 64-block coalesced slice-reduce + 1-block
// finalize. No memset (all exclusive writes). Manual 2-deep load
// pipeline, launch_bounds(256,4) for MLP headroom.
//
// B=16384, N_NARR=128, N_SUB=1024, K=8, GAMMA=2, weights (1,1,0.5).

#define BDIM 256
#define NROWS 16384
#define NNARR 128
#define NSUB 1024

#define NSLICES 8
#define SUBC 128                           // sub cols per slice
#define NARRC 16                           // narr cols per slice
#define ROWS_PER_CHUNK 64
#define NCHUNKS (NROWS / ROWS_PER_CHUNK)   // 256
#define NBLOCKS (NCHUNKS * NSLICES)        // 2048
#define ROWS_PER_PASS 8                    // 256 thr / 32 col-quads
#define ITERS (ROWS_PER_CHUNK / ROWS_PER_PASS)  // 8

// per-block partial layout (floats): [32 quads][As4|Cs4|ss4] | narr | sc
#define PE_NARR 384     // 16 cols x {An,Cn,ns}
#define PE_SC   432     // {fn,fs,hier}
#define PUSED   435
#define PSTRIDE 448     // 1792B, 16B aligned

#define NGRP 8                             // chunk groups in sreduce
#define CHUNKS_PER_GRP (NCHUNKS / NGRP)    // 32
#define TSTRIDE 448                        // tmp table stride (64 tables)

__device__ __forceinline__ void bce_pieces(float x, float& sp_p, float& sp_m, float& sig) {
    float a = fabsf(x);
    float e = __expf(-a);              // exp(-|x|) in (0,1]
    float l = __logf(1.0f + e);        // ~log1p(e); err ~1e-7, fine after /2M
    sp_p = fmaxf(x, 0.0f) + l;
    sp_m = sp_p - x;
    float inv = __builtin_amdgcn_rcpf(1.0f + e);
    sig = (x >= 0.0f) ? inv : e * inv;
}

__global__ __launch_bounds__(BDIM, 4) void ncl_main(
    const float* __restrict__ nlog, const float* __restrict__ slog,
    const int*   __restrict__ nlab, const int*   __restrict__ slab,
    float* __restrict__ P)
{
    __shared__ float lsub[4][32][12];  // per-wave per-col-quad {As,Cs,ss}
    __shared__ float lnar[4][16][3];   // per-wave per-narrcol {An,Cn,ns}
    __shared__ float lsc[4][3];        // per-wave {fn,fs,hier}

    const int t     = threadIdx.x;
    const int j     = blockIdx.x & (NSLICES - 1);   // col slice (== XCD id)
    const int chunk = blockIdx.x >> 3;              // row chunk
    const int q  = t & 31;       // sub col-quad within slice (4 cols)
    const int ro = t >> 5;       // row offset 0..7 within a pass
    const int cl = q >> 1;       // local narr col 0..15 (quad pair = 1 group)
    const bool evenq = (q & 1) == 0;

    const int r0 = chunk * ROWS_PER_CHUNK + ro;
    const float* sp = slog + (size_t)r0 * NSUB  + j * SUBC  + 4 * q;
    const int*   yp = slab + (size_t)r0 * NSUB  + j * SUBC  + 4 * q;
    const float* np = nlog + (size_t)r0 * NNARR + j * NARRC + cl;
    const int*   mp = nlab + (size_t)r0 * NNARR + j * NARRC + cl;

    float As[4] = {0,0,0,0}, Cs[4] = {0,0,0,0}, ssum[4] = {0,0,0,0};
    float An = 0.f, Cn = 0.f, ns = 0.f, fn = 0.f, fs = 0.f, hier = 0.f;

    // 2-deep software pipeline: next iteration's loads in flight under
    // the current iteration's VALU work.
    float4 xs = *(const float4*)sp;
    int4   ys = *(const int4*)  yp;
    float  nx   = *np;
    float  posv = (float)*mp;

    #pragma unroll
    for (int it = 0; it < ITERS; ++it) {
        float4 xs_n; int4 ys_n; float nx_n = 0.f, posv_n = 0.f;
        if (it + 1 < ITERS) {
            const size_t so = (size_t)(it + 1) * ROWS_PER_PASS * NSUB;
            const size_t no = (size_t)(it + 1) * ROWS_PER_PASS * NNARR;
            xs_n   = *(const float4*)(sp + so);
            ys_n   = *(const int4*)  (yp + so);
            nx_n   = np[no];
            posv_n = (float)mp[no];
        }

        float nsp_p, nsp_m, nsig;
        bce_pieces(nx, nsp_p, nsp_m, nsig);

        const float xv[4] = {xs.x, xs.y, xs.z, xs.w};
        const float yv[4] = {(float)ys.x, (float)ys.y, (float)ys.z, (float)ys.w};
        float mymax = 0.0f;
        #pragma unroll
        for (int k = 0; k < 4; ++k) {
            float sp_p, sp_m, sig;
            bce_pieces(xv[k], sp_p, sp_m, sig);
            float y = yv[k];
            As[k]   += posv * y * sp_m;
            Cs[k]   += posv * (1.0f - y) * sp_p;
            ssum[k] += y;
            float om = 1.0f - sig;
            fs += om * om * y * (-sp_m);     // log_sigmoid(x) = -softplus(-x)
            mymax = fmaxf(mymax, sig);
        }
        // group of 8 sub cols = adjacent quad pair (t, t^1): same row, same cl
        float gmax = fmaxf(mymax, __shfl_xor(mymax, 1, 64));
        if (evenq) {
            hier += fmaxf(gmax - nsig, 0.0f) * posv;
            An += posv * nsp_m;
            Cn += (1.0f - posv) * nsp_p;
            ns += posv;
            float om = 1.0f - nsig;
            fn += om * om * posv * (-nsp_m);
        }

        if (it + 1 < ITERS) { xs = xs_n; ys = ys_n; nx = nx_n; posv = posv_n; }
    }

    // lanes l and l+32 share q (differ in ro): one stride-32 butterfly folds
    // the wave's two row-sets. Narr values live only on even-q lanes.
    #pragma unroll
    for (int k = 0; k < 4; ++k) {
        As[k]   += __shfl_xor(As[k],   32, 64);
        Cs[k]   += __shfl_xor(Cs[k],   32, 64);
        ssum[k] += __shfl_xor(ssum[k], 32, 64);
    }
    An += __shfl_xor(An, 32, 64);
    Cn += __shfl_xor(Cn, 32, 64);
    ns += __shfl_xor(ns, 32, 64);
    // full-wave butterfly for the scalar partials
    #pragma unroll
    for (int m = 1; m <= 32; m <<= 1) {
        fn   += __shfl_xor(fn,   m, 64);
        fs   += __shfl_xor(fs,   m, 64);
        hier += __shfl_xor(hier, m, 64);
    }

    const int w = t >> 6, lane = t & 63;
    if (lane < 32) {
        #pragma unroll
        for (int k = 0; k < 4; ++k) {
            lsub[w][lane][k]     = As[k];
            lsub[w][lane][4 + k] = Cs[k];
            lsub[w][lane][8 + k] = ssum[k];
        }
        if ((lane & 1) == 0) {
            lnar[w][lane >> 1][0] = An;
            lnar[w][lane >> 1][1] = Cn;
            lnar[w][lane >> 1][2] = ns;
        }
    }
    if (lane == 0) { lsc[w][0] = fn; lsc[w][1] = fs; lsc[w][2] = hier; }
    __syncthreads();

    // exclusive per-block partial: plain stores, no atomics.
    float* const Pb = P + (size_t)blockIdx.x * PSTRIDE;
    if (t < 32) {
        float a[12];
        #pragma unroll
        for (int k = 0; k < 12; ++k)
            a[k] = lsub[0][t][k] + lsub[1][t][k] + lsub[2][t][k] + lsub[3][t][k];
        *(float4*)(Pb + t * 12 + 0) = make_float4(a[0], a[1], a[2],  a[3]);
        *(float4*)(Pb + t * 12 + 4) = make_float4(a[4], a[5], a[6],  a[7]);
        *(float4*)(Pb + t * 12 + 8) = make_float4(a[8], a[9], a[10], a[11]);
    } else if (t < 48) {
        const int c = t - 32;
        Pb[PE_NARR + c * 3 + 0] = lnar[0][c][0] + lnar[1][c][0] + lnar[2][c][0] + lnar[3][c][0];
        Pb[PE_NARR + c * 3 + 1] = lnar[0][c][1] + lnar[1][c][1] + lnar[2][c][1] + lnar[3][c][1];
        Pb[PE_NARR + c * 3 + 2] = lnar[0][c][2] + lnar[1][c][2] + lnar[2][c][2] + lnar[3][c][2];
    } else if (t == 48) {
        Pb[PE_SC + 0] = lsc[0][0] + lsc[1][0] + lsc[2][0] + lsc[3][0];
        Pb[PE_SC + 1] = lsc[0][1] + lsc[1][1] + lsc[2][1] + lsc[3][1];
        Pb[PE_SC + 2] = lsc[0][2] + lsc[1][2] + lsc[2][2] + lsc[3][2];
    }
}

// slice-reduce: block (g, j) sums partials of slice j over 32 chunks.
// Reads are fully coalesced (consecutive t -> consecutive floats).
__global__ __launch_bounds__(256) void ncl_sreduce(const float* __restrict__ P,
                                                   float* __restrict__ tmp)
{
    const int g = blockIdx.x;          // chunk group 0..7
    const int j = blockIdx.y;          // slice 0..7
    const int t = threadIdx.x;
    const bool hi = t < (PSTRIDE - 256);   // second element e=t+256 valid

    float s0 = 0.f, s1 = 0.f;
    #pragma unroll 4
    for (int cc = 0; cc < CHUNKS_PER_GRP; ++cc) {
        const int c = g * CHUNKS_PER_GRP + cc;
        const float* p = P + (size_t)(c * NSLICES + j) * PSTRIDE;
        s0 += p[t];
        if (hi) s1 += p[t + 256];
    }
    float* o = tmp + (size_t)(g * NSLICES + j) * TSTRIDE;
    o[t] = s0;
    if (hi) o[t + 256] = s1;
}

__global__ __launch_bounds__(1024) void ncl_finalize(const float* __restrict__ tmp,
                                                     float* __restrict__ out)
{
    __shared__ float sr[6][16];
    const int t = threadIdx.x;
    const float Bf = (float)NROWS;

    // sub column t: slice j owns cols [j*128, j*128+128)
    {
    }
    const int j  = t >> 7;
    const int cs = t & 127;
    const int q  = cs >> 2;
    const int k  = cs & 3;
    float As = 0.f, Csv = 0.f, ss = 0.f;
    #pragma unroll
    for (int g = 0; g < NGRP; ++g) {
        const float* p = tmp + (size_t)(g * NSLICES + j) * TSTRIDE + q * 12 + k;
        As  += p[0];
        Csv += p[4];
        ss  += p[8];
    }
    float spw = fminf(fmaxf((Bf - ss) / (ss + 1e-6f), 1.0f), 50.0f);
    float sub_part = spw * As + Csv;

    float narr_part = 0.f, valid_part = 0.f;
    if (t < NNARR) {
        const int jn = t >> 4, c = t & 15;
        float An = 0.f, Cn = 0.f, ns = 0.f;
        #pragma unroll
        for (int g = 0; g < NGRP; ++g) {
            const float* p = tmp + (size_t)(g * NSLICES + jn) * TSTRIDE + PE_NARR + c * 3;
            An += p[0]; Cn += p[1]; ns += p[2];
        }
        float npw = fminf(fmaxf((Bf - ns) / (ns + 1e-6f), 1.0f), 50.0f);
        narr_part  = npw * An + Cn;
        valid_part = ns;
    }

    float fn_p = 0.f, fs_p = 0.f, hier_p = 0.f;
    if (t < NGRP * NSLICES) {
        const float* p = tmp + (size_t)t * TSTRIDE + PE_SC;
        fn_p = p[0]; fs_p = p[1]; hier_p = p[2];
    }

    #pragma unroll
    for (int off = 32; off; off >>= 1) {
        sub_part   += __shfl_down(sub_part,   off, 64);
        narr_part  += __shfl_down(narr_part,  off, 64);
        valid_part += __shfl_down(valid_part, off, 64);
        fn_p       += __shfl_down(fn_p,       off, 64);
        fs_p       += __shfl_down(fs_p,       off, 64);
        hier_p     += __shfl_down(hier_p,     off, 64);
    }
    if ((t & 63) == 0) {
        int w = t >> 6;
        sr[0][w] = sub_part; sr[1][w] = narr_part; sr[2][w] = valid_part;
        sr[3][w] = fn_p;     sr[4][w] = fs_p;      sr[5][w] = hier_p;
    }
    __syncthreads();
    if (t == 0) {
        float sub_tot = 0.f, narr_tot = 0.f, valid = 0.f;
        float fn = 0.f, fs = 0.f, hier = 0.f;
        #pragma unroll
        for (int i = 0; i < 16; ++i) {
            sub_tot += sr[0][i]; narr_tot += sr[1][i]; valid += sr[2][i];
            fn += sr[3][i]; fs += sr[4][i]; hier += sr[5][i];
        }

        float narrative_loss = narr_tot / (Bf * (float)NNARR);
        float sub_loss = (valid > 0.0f) ? (sub_tot * (1.0f / 8.0f)) / fmaxf(valid, 1.0f) : 0.0f;
        float nf = fn / (Bf * (float)NNARR);
        float sf = fs / (Bf * (float)NSUB);
        float hier_loss = hier / Bf;

        out[0] = (narrative_loss - 0.1f * nf)
               + (sub_loss       - 0.1f * sf)
               + 0.5f * hier_loss;
    }
}

extern "C" void kernel_launch(void* const* d_in, const int* in_sizes, int n_in,
                              void* d_out, int out_size, void* d_ws, size_t ws_size,
                              hipStream_t stream) {
    const float* nlog = (const float*)d_in[0];
    const float* slog = (const float*)d_in[1];
    const int*   nlab = (const int*)d_in[2];
    const int*   slab = (const int*)d_in[3];
    float* P   = (float*)d_ws;                        // 2048 * 448 floats
    float* tmp = P + (size_t)NBLOCKS * PSTRIDE;       // 64 * 448 floats
    float* out = (float*)d_out;

    // all workspace cells are exclusively written before read: no memset.
    ncl_main<<<NBLOCKS, BDIM, 0, stream>>>(nlog, slog, nlab, slab, P);
    dim3 gr(NGRP, NSLICES);
    ncl_sreduce<<<gr, 256, 0, stream>>>(P, tmp);
    ncl_finalize<<<1, 1024, 0, stream>>>(tmp, out);
}